// Round 8
// baseline (53.852 us; speedup 1.0000x reference)
//
#include <hip/hip_runtime.h>

#define NB 8
#define C_IN 64
#define HW 65536      // 256*256
#define CF 256
#define FHW 4096      // 64*64
#define NSEG 256
#define CPG 16        // channels per input block
#define CGRP 4        // channel groups (CGRP*CPG = C_IN)
#define PBLK 64       // pixel chunks per batch (1024 px each)
#define MAGIC 0x13579BDFu
#define AG __HIP_MEMORY_SCOPE_AGENT

// ws layout (floats):
// fsum[NB][FHW] @ 0       (32768)
// sxg [NB][NSEG] @ 32768
// scg [NB][NSEG] @ 34816
// sfg [NB][NSEG] @ 36864
// u32 ppbits[NB], bflags[NB] @ 38912

// ---------- A: feature channel-sum (512 blocks) + zero accumulators ----------
__global__ __launch_bounds__(256) void featsum_kernel(
    const float* __restrict__ feat, float* __restrict__ fsum,
    float* __restrict__ sxg, float* __restrict__ scg,
    float* __restrict__ sfg) {
  __shared__ float4 lred[256];   // [16 ch-grp][16 col]
  __shared__ float4 lred2[64];   // [4][16]
  int b = blockIdx.y, e = blockIdx.x, t = threadIdx.x;
  if (e < 3) {
    float* z = (e == 0) ? sxg : (e == 1) ? scg : sfg;
    z[b * NSEG + t] = 0.f;
  }
  int q = t & 15, cg = t >> 4;
  const float4* f4 = (const float4*)(feat + (size_t)b * CF * FHW);
  int col = e * 16 + q;
  float4 s = make_float4(0.f, 0.f, 0.f, 0.f);
#pragma unroll
  for (int k = 0; k < 16; ++k) {
    float4 v = f4[(size_t)(cg + k * 16) * (FHW / 4) + col];
    s.x += v.x; s.y += v.y; s.z += v.z; s.w += v.w;
  }
  lred[cg * 16 + q] = s;
  __syncthreads();
  if (t < 64) {
    int q2 = t & 15, g2 = t >> 4;
    float4 a = lred[(g2 * 4 + 0) * 16 + q2];
    float4 b1 = lred[(g2 * 4 + 1) * 16 + q2];
    float4 c1 = lred[(g2 * 4 + 2) * 16 + q2];
    float4 d = lred[(g2 * 4 + 3) * 16 + q2];
    a.x += b1.x + c1.x + d.x; a.y += b1.y + c1.y + d.y;
    a.z += b1.z + c1.z + d.z; a.w += b1.w + c1.w + d.w;
    lred2[t] = a;
  }
  __syncthreads();
  if (t < 16) {
    float4 a = lred2[t], b1 = lred2[16 + t], c1 = lred2[32 + t], d = lred2[48 + t];
    a.x += b1.x + c1.x + d.x; a.y += b1.y + c1.y + d.y;
    a.z += b1.z + c1.z + d.z; a.w += b1.w + c1.w + d.w;
    ((float4*)fsum)[(size_t)b * (FHW / 4) + col] = a;
  }
}

// ---------- B: mixed dispatch — input streaming blocks + bilinear blocks ----------
__global__ __launch_bounds__(256) void main_kernel(
    const float* __restrict__ input, const int* __restrict__ sp,
    const float* __restrict__ fsum, float* __restrict__ sxg,
    float* __restrict__ scg, float* __restrict__ sfg) {
  __shared__ float fls[FHW];            // bilinear blocks only
  __shared__ float bx[NSEG];            // input blocks: xs bins; shared reuse ok
  __shared__ float bc[NSEG], bf[NSEG];  // bilinear blocks
  int b = blockIdx.y, x = blockIdx.x, t = threadIdx.x;
  const int4* sp4 = (const int4*)(sp + (size_t)b * HW);

  if (x < PBLK * CGRP) {
    // input block: pixel chunk pix, channels [g*16, g*16+16)
    int pix = x >> 2, g = x & 3;
    bx[t] = 0.f;
    __syncthreads();
    int v0 = pix * 256 + t;
    const float4* in4 = (const float4*)(input + (size_t)b * C_IN * HW);
    float4 xs = make_float4(0.f, 0.f, 0.f, 0.f);
#pragma unroll
    for (int k = 0; k < CPG; ++k) {
      float4 v = in4[(size_t)(g * CPG + k) * (HW / 4) + v0];
      xs.x += v.x; xs.y += v.y; xs.z += v.z; xs.w += v.w;
    }
    int4 sv = sp4[v0];
    atomicAdd(&bx[sv.x], xs.x);
    atomicAdd(&bx[sv.y], xs.y);
    atomicAdd(&bx[sv.z], xs.z);
    atomicAdd(&bx[sv.w], xs.w);
    __syncthreads();
    atomicAdd(&sxg[b * NSEG + t], bx[t]);
    return;
  }

  // bilinear block: pixel chunk pix = x - 256
  int pix = x - PBLK * CGRP;
  {
    const float4* s4 = (const float4*)(fsum + (size_t)b * FHW);
    float4* d4 = (float4*)fls;
#pragma unroll
    for (int i = 0; i < 4; ++i) d4[i * 256 + t] = s4[i * 256 + t];
  }
  bc[t] = 0.f; bf[t] = 0.f;
  __syncthreads();
  int v0 = pix * 256 + t;
  int4 sv = sp4[v0];
  int p0 = v0 * 4;
  int y = p0 >> 8;
  float cy = (float)y * (63.0f / 255.0f);
  int iy = (int)cy; float ty = cy - (float)iy; int iy1 = min(iy + 1, 63);
  int svv[4] = {sv.x, sv.y, sv.z, sv.w};
#pragma unroll
  for (int kk = 0; kk < 4; ++kk) {
    int xx = (p0 + kk) & 255;
    float cx = (float)xx * (63.0f / 255.0f);
    int ix = (int)cx; float tx = cx - (float)ix; int ix1 = min(ix + 1, 63);
    float f00 = fls[iy * 64 + ix],  f10 = fls[iy1 * 64 + ix];
    float f01 = fls[iy * 64 + ix1], f11 = fls[iy1 * 64 + ix1];
    float a0 = f00 * (1.f - ty) + f10 * ty;
    float a1 = f01 * (1.f - ty) + f11 * ty;
    atomicAdd(&bf[svv[kk]], a0 * (1.f - tx) + a1 * tx);
    atomicAdd(&bc[svv[kk]], 1.f);
  }
  __syncthreads();
  atomicAdd(&scg[b * NSEG + t], bc[t]);
  atomicAdd(&sfg[b * NSEG + t], bf[t]);
}

// ---------- C: means, pair sum, cross-batch finish (8 blocks) ----------
__global__ __launch_bounds__(256) void pairfinal_kernel(
    const float* __restrict__ sxg, const float* __restrict__ scg,
    const float* __restrict__ sfg,
    unsigned* __restrict__ ppbits, unsigned* __restrict__ bflags,
    float* __restrict__ out) {
  __shared__ float m1[NSEG], m2[NSEG];
  __shared__ float red[4];
  int b = blockIdx.x, t = threadIdx.x;
  {
    float cnt = scg[b * NSEG + t];
    m1[t] = sxg[b * NSEG + t] / (cnt * 64.0f);
    m2[t] = sfg[b * NSEG + t] / (cnt * 256.0f);
  }
  __syncthreads();
  float a1 = m1[t], a2 = m2[t], acc = 0.f;
#pragma unroll 8
  for (int j = 0; j < NSEG; ++j)
    acc += fabsf(fabsf(a1 - m1[j]) - fabsf(a2 - m2[j]));
#pragma unroll
  for (int off = 32; off; off >>= 1) acc += __shfl_down(acc, off);
  if ((t & 63) == 0) red[t >> 6] = acc;
  __syncthreads();
  if (t == 0) {
    float s = red[0] + red[1] + red[2] + red[3];
    __hip_atomic_store(&ppbits[b], __float_as_uint(s), __ATOMIC_RELAXED, AG);
    __hip_atomic_store(&bflags[b], MAGIC, __ATOMIC_RELEASE, AG);
    if (b == 0) {
      float tot = s;
      for (int ob = 1; ob < NB; ++ob) {
        while (__hip_atomic_load(&bflags[ob], __ATOMIC_ACQUIRE, AG) != MAGIC)
          __builtin_amdgcn_s_sleep(2);
        tot += __uint_as_float(__hip_atomic_load(
            &ppbits[ob], __ATOMIC_RELAXED, AG));
        __hip_atomic_store(&bflags[ob], 0u, __ATOMIC_RELAXED, AG);
      }
      out[0] = tot / 524288.0f;  // NB * NSEG * NSEG
      __hip_atomic_store(&bflags[0], 0u, __ATOMIC_RELAXED, AG);
    }
  }
}

extern "C" void kernel_launch(void* const* d_in, const int* in_sizes, int n_in,
                              void* d_out, int out_size, void* d_ws, size_t ws_size,
                              hipStream_t stream) {
  const float* input   = (const float*)d_in[0];
  const float* feature = (const float*)d_in[1];
  const int*   sp      = (const int*)d_in[2];
  float* ws = (float*)d_ws;
  float*    fsum   = ws;
  float*    sxg    = ws + 32768;
  float*    scg    = ws + 34816;
  float*    sfg    = ws + 36864;
  unsigned* ppbits = (unsigned*)(ws + 38912);
  unsigned* bflags = ppbits + NB;

  featsum_kernel<<<dim3(64, NB), 256, 0, stream>>>(feature, fsum, sxg, scg, sfg);
  main_kernel<<<dim3(PBLK * CGRP + PBLK, NB), 256, 0, stream>>>(
      input, sp, fsum, sxg, scg, sfg);
  pairfinal_kernel<<<dim3(NB), 256, 0, stream>>>(sxg, scg, sfg, ppbits, bflags,
                                                 (float*)d_out);
}

// Round 9
// 46.763 us; speedup vs baseline: 1.1516x; 1.1516x over previous
//
#include <hip/hip_runtime.h>

#define NB 8
#define C_IN 64
#define HW 65536      // 256*256
#define CF 256
#define FHW 4096      // 64*64
#define NSEG 256
#define FBLK 16       // featsum blocks per batch
#define MBLK 64       // input blocks per batch
#define TOTB 80
#define MAGIC 0x13579BDFu
#define AG __HIP_MEMORY_SCOPE_AGENT

// ws layout (floats):
// fsum     [NB][FHW]            @ 0       (32768)
// seg_part [NB][MBLK][2][NSEG]  @ 32768   (262144)   0=xsum,1=cnt
// binf_part[NB][MBLK][NSEG]     @ 294912  (131072)
// u32: ppbits[NB], bflags[NB]   @ 425984

// ---------- k1: featsum strips + input stream/histogram (mixed, 640 blocks) ----------
__global__ __launch_bounds__(256) void k1(
    const float* __restrict__ input, const int* __restrict__ sp,
    const float* __restrict__ feat,
    float* __restrict__ fsum, float* __restrict__ seg_part) {
  __shared__ float smem[1024];   // featsum: float4 lred[4][64]; input: 2*NSEG bins
  int b = blockIdx.y, e = blockIdx.x, t = threadIdx.x;

  if (e < FBLK) {
    // featsum strip: 256 px (64 float4 cols), all 256 channels, fully reduced
    int q = t & 63, cg = t >> 6;
    const float4* f4 = (const float4*)(feat + (size_t)b * CF * FHW);
    int col = e * 64 + q;
    float4 s = make_float4(0.f, 0.f, 0.f, 0.f);
#pragma unroll 8
    for (int c = cg; c < CF; c += 4) {
      float4 v = f4[(size_t)c * (FHW / 4) + col];
      s.x += v.x; s.y += v.y; s.z += v.z; s.w += v.w;
    }
    float4* lred = (float4*)smem;                  // [4][64] float4
    lred[cg * 64 + q] = s;
    __syncthreads();
    if (t < 64) {
      float4 a = lred[t], b1 = lred[64 + t], c1 = lred[128 + t], d = lred[192 + t];
      a.x += b1.x + c1.x + d.x; a.y += b1.y + c1.y + d.y;
      a.z += b1.z + c1.z + d.z; a.w += b1.w + c1.w + d.w;
      ((float4*)fsum)[(size_t)b * (FHW / 4) + e * 64 + t] = a;
    }
    return;
  }

  // input block: channel-sum + count histogram per segment
  int blk = e - FBLK;
  float* bin_x = smem;
  float* bin_c = smem + NSEG;
  bin_x[t] = 0.f; bin_c[t] = 0.f;
  __syncthreads();
  int v0 = blk * 256 + t;
  const float4* in4 = (const float4*)(input + (size_t)b * C_IN * HW);
  float4 xs = make_float4(0.f, 0.f, 0.f, 0.f);
#pragma unroll
  for (int c = 0; c < C_IN; ++c) {
    float4 v = in4[(size_t)c * (HW / 4) + v0];
    xs.x += v.x; xs.y += v.y; xs.z += v.z; xs.w += v.w;
  }
  int4 sv = ((const int4*)(sp + (size_t)b * HW))[v0];
  atomicAdd(&bin_x[sv.x], xs.x); atomicAdd(&bin_c[sv.x], 1.f);
  atomicAdd(&bin_x[sv.y], xs.y); atomicAdd(&bin_c[sv.y], 1.f);
  atomicAdd(&bin_x[sv.z], xs.z); atomicAdd(&bin_c[sv.z], 1.f);
  atomicAdd(&bin_x[sv.w], xs.w); atomicAdd(&bin_c[sv.w], 1.f);
  __syncthreads();
  float* sb = seg_part + (size_t)(b * MBLK + blk) * 2 * NSEG;
  sb[t] = bin_x[t];
  sb[NSEG + t] = bin_c[t];
}

// ---------- k2: WIDE bilinear (64 blocks/batch = 512 blocks) ----------
__global__ __launch_bounds__(256) void k2(
    const int* __restrict__ sp, const float* __restrict__ fsum,
    float* __restrict__ binf_part) {
  __shared__ float fls[FHW];
  __shared__ float binf[NSEG];
  int blk = blockIdx.x, b = blockIdx.y, t = threadIdx.x;
  {
    const float4* s4 = (const float4*)(fsum + (size_t)b * FHW);
    float4* d4 = (float4*)fls;
#pragma unroll
    for (int i = 0; i < 4; ++i) d4[i * 256 + t] = s4[i * 256 + t];
  }
  binf[t] = 0.f;
  __syncthreads();
  int v0 = blk * 256 + t;
  int4 sv = ((const int4*)(sp + (size_t)b * HW))[v0];
  int p0 = v0 * 4;
  int y = p0 >> 8;
  float cy = (float)y * (63.0f / 255.0f);
  int iy = (int)cy; float ty = cy - (float)iy; int iy1 = min(iy + 1, 63);
  int svv[4] = {sv.x, sv.y, sv.z, sv.w};
#pragma unroll
  for (int kk = 0; kk < 4; ++kk) {
    int x = (p0 + kk) & 255;
    float cx = (float)x * (63.0f / 255.0f);
    int ix = (int)cx; float tx = cx - (float)ix; int ix1 = min(ix + 1, 63);
    float f00 = fls[iy * 64 + ix],  f10 = fls[iy1 * 64 + ix];
    float f01 = fls[iy * 64 + ix1], f11 = fls[iy1 * 64 + ix1];
    float a0 = f00 * (1.f - ty) + f10 * ty;
    float a1 = f01 * (1.f - ty) + f11 * ty;
    atomicAdd(&binf[svv[kk]], a0 * (1.f - tx) + a1 * tx);
  }
  __syncthreads();
  binf_part[(size_t)(b * MBLK + blk) * NSEG + t] = binf[t];
}

// ---------- k3: reduce partials, means, pair sum, cross-batch finish ----------
__global__ __launch_bounds__(1024) void k3(
    const float* __restrict__ seg_part, const float* __restrict__ binf_part,
    unsigned* __restrict__ ppbits, unsigned* __restrict__ bflags,
    float* __restrict__ out) {
  __shared__ float s2[2 * NSEG];
  __shared__ float sf[NSEG];
  __shared__ float m1[NSEG], m2[NSEG];
  __shared__ float red[16];
  int b = blockIdx.x, t = threadIdx.x;
  if (t < 2 * NSEG) {
    const float* base = seg_part + (size_t)b * MBLK * 2 * NSEG + t;
    float s = 0.f;
#pragma unroll
    for (int k = 0; k < MBLK; ++k) s += base[k * 2 * NSEG];
    s2[t] = s;
  } else if (t < 3 * NSEG) {
    int u = t - 2 * NSEG;
    const float* base = binf_part + (size_t)b * MBLK * NSEG + u;
    float s = 0.f;
#pragma unroll
    for (int k = 0; k < MBLK; ++k) s += base[k * NSEG];
    sf[u] = s;
  }
  __syncthreads();
  if (t < NSEG) {
    float cnt = s2[NSEG + t];
    m1[t] = s2[t] / (cnt * 64.0f);
    m2[t] = sf[t] / (cnt * 256.0f);
  }
  __syncthreads();
  int i = t & 255, j0 = (t >> 8) * 64;
  float a1 = m1[i], a2 = m2[i], acc = 0.f;
#pragma unroll
  for (int jj = 0; jj < 64; ++jj) {
    int j = j0 + jj;
    acc += fabsf(fabsf(a1 - m1[j]) - fabsf(a2 - m2[j]));
  }
#pragma unroll
  for (int off = 32; off; off >>= 1) acc += __shfl_down(acc, off);
  if ((t & 63) == 0) red[t >> 6] = acc;
  __syncthreads();
  if (t == 0) {
    float s = 0.f;
#pragma unroll
    for (int w = 0; w < 16; ++w) s += red[w];
    __hip_atomic_store(&ppbits[b], __float_as_uint(s), __ATOMIC_RELAXED, AG);
    __hip_atomic_store(&bflags[b], MAGIC, __ATOMIC_RELEASE, AG);
    if (b == 0) {
      float tot = s;
      for (int ob = 1; ob < NB; ++ob) {
        while (__hip_atomic_load(&bflags[ob], __ATOMIC_ACQUIRE, AG) != MAGIC)
          __builtin_amdgcn_s_sleep(2);
        tot += __uint_as_float(__hip_atomic_load(
            &ppbits[ob], __ATOMIC_RELAXED, AG));
        __hip_atomic_store(&bflags[ob], 0u, __ATOMIC_RELAXED, AG);
      }
      out[0] = tot / 524288.0f;  // NB * NSEG * NSEG
      __hip_atomic_store(&bflags[0], 0u, __ATOMIC_RELAXED, AG);
    }
  }
}

extern "C" void kernel_launch(void* const* d_in, const int* in_sizes, int n_in,
                              void* d_out, int out_size, void* d_ws, size_t ws_size,
                              hipStream_t stream) {
  const float* input   = (const float*)d_in[0];
  const float* feature = (const float*)d_in[1];
  const int*   sp      = (const int*)d_in[2];
  float* ws = (float*)d_ws;
  float*    fsum      = ws;
  float*    seg_part  = ws + (size_t)NB * FHW;
  float*    binf_part = seg_part + (size_t)NB * MBLK * 2 * NSEG;
  unsigned* ppbits    = (unsigned*)(binf_part + (size_t)NB * MBLK * NSEG);
  unsigned* bflags    = ppbits + NB;

  k1<<<dim3(TOTB, NB), 256, 0, stream>>>(input, sp, feature, fsum, seg_part);
  k2<<<dim3(MBLK, NB), 256, 0, stream>>>(sp, fsum, binf_part);
  k3<<<dim3(NB), 1024, 0, stream>>>(seg_part, binf_part, ppbits, bflags,
                                    (float*)d_out);
}